// Round 11
// baseline (1194.749 us; speedup 1.0000x reference)
//
#include <hip/hip_runtime.h>
#include <cstdint>
#include <cstddef>

namespace {

constexpr int B_ = 8;
constexpr int D_ = 512;
constexpr int N_ = 16384;
constexpr int R_ = 64;
constexpr float EPS_ = 1e-6f;
constexpr float INVT_ = 100.0f;

typedef __attribute__((ext_vector_type(4))) float f32x4;
typedef __attribute__((ext_vector_type(8))) short s16x8;
typedef __attribute__((ext_vector_type(4))) short s16x4;

#define MFMA16(A, Bv, C) __builtin_amdgcn_mfma_f32_16x16x32_bf16(A, Bv, C, 0, 0, 0)

#define VMW(n) asm volatile("s_waitcnt vmcnt(" #n ")" ::: "memory")
#define LGKM0 asm volatile("s_waitcnt lgkmcnt(0)" ::: "memory")
#define SCHEDB __builtin_amdgcn_sched_barrier(0)
#define BARRIER do { SCHEDB; __builtin_amdgcn_s_barrier(); SCHEDB; } while (0)

typedef __attribute__((address_space(3))) unsigned int lds_u32_t;
typedef const __attribute__((address_space(1))) unsigned int glb_u32_t;

__device__ __forceinline__ void gl2lds16(const void* g, void* l) {
    __builtin_amdgcn_global_load_lds((glb_u32_t*)g, (lds_u32_t*)l, 16, 0, 0);
}

__device__ __forceinline__ unsigned short f2bf(float x) {
    unsigned int u = __float_as_uint(x);
    return (unsigned short)((u + 0x7fffu + ((u >> 16) & 1u)) >> 16);
}
__device__ __forceinline__ float bf2f(unsigned short u) {
    return __uint_as_float(((unsigned int)u) << 16);
}
__device__ __forceinline__ s16x8 ld8(const unsigned short* p) {
    return *reinterpret_cast<const s16x8*>(p);
}

// Stage a 16-row x 1KB tile into LDS: wave w stages rows w*4..w*4+4 (4 ops).
// Source col pre-XOR'd with ((row&7)<<4) so swizzled reads are conflict-free.
__device__ __forceinline__ void stage16(const unsigned short* __restrict__ rowbase,
        size_t rstride_elems, unsigned short* __restrict__ buf, int w, int lane) {
#pragma unroll
    for (int i = 0; i < 4; ++i) {
        int r = w * 4 + i;
        const char* src = reinterpret_cast<const char*>(rowbase + (size_t)r * rstride_elems)
                        + ((lane << 4) ^ ((r & 7) << 4));
        gl2lds16(src, reinterpret_cast<char*>(buf) + r * 1024);
    }
}
// read B-frag: row (0..15), k-step ks, h4 = lane>>4
__device__ __forceinline__ s16x8 read_t16(const unsigned short* buf, int row, int ks, int h4) {
    return *reinterpret_cast<const s16x8*>(reinterpret_cast<const char*>(buf)
        + row * 1024 + ((ks * 64 + h4 * 16) ^ ((row & 7) << 4)));
}
// Stage a 16-row x 128B Cnr tile (2 KB): wave's (w&1) half; waves 2,3 duplicate 0,1.
__device__ __forceinline__ void stage_c16(const unsigned short* __restrict__ cnr_n0,
        unsigned short* __restrict__ buf, int w, int lane) {
    int h = w & 1;
    int row = h * 8 + (lane >> 3);
    const char* src = reinterpret_cast<const char*>(cnr_n0 + (size_t)row * R_)
                    + ((((lane & 7) ^ (row & 7))) << 4);
    gl2lds16(src, reinterpret_cast<char*>(buf) + h * 1024);
}
__device__ __forceinline__ s16x8 read_c16(const unsigned short* buf, int row, int ks, int h4) {
    return *reinterpret_cast<const s16x8*>(reinterpret_cast<const char*>(buf)
        + row * 128 + ((ks * 64 + h4 * 16) ^ ((row & 7) << 4)));
}
__device__ __forceinline__ float read_c_scalar(const unsigned short* buf, int row, int r) {
    return bf2f(*reinterpret_cast<const unsigned short*>(
        reinterpret_cast<const char*>(buf) + row * 128 + ((r * 2) ^ ((row & 7) << 4))));
}

// ---------------- convert: X fp32 -> X_hi TILED [dt][nt][16][512], XT_hi/XT_lo [N][D] ----
// 64x64 tile (16KB LDS, 24 VGPR, ~74% occupancy — R6-proven form).
// Xhi tiled layout: element (d,n) at ((d>>4)*32 + (n>>9))*8192 + (d&15)*512 + (n&511).
__global__ __launch_bounds__(256) void k_convert(const float* __restrict__ X,
        unsigned short* __restrict__ Xhi, unsigned short* __restrict__ XThi,
        unsigned short* __restrict__ XTlo, int have_lo) {
    __shared__ f32x4 lds4[64 * 16];   // 16 KB, row stride 16 vectors (64 floats), swizzled
    int id = blockIdx.x;
    int nblk = id & 255, dblk = (id >> 8) & 7, b = id >> 11;
    int t = threadIdx.x;
    int d = t >> 2, c0 = (t & 3) * 16;
    const float* Xb = X + ((size_t)b * D_ + dblk * 64) * N_ + (size_t)nblk * 64;
    f32x4 v[4];
#pragma unroll
    for (int i = 0; i < 4; ++i)
        v[i] = *reinterpret_cast<const f32x4*>(Xb + (size_t)d * N_ + c0 + 4 * i);
    {
        int swz = (d ^ (d >> 3)) & 7;
#pragma unroll
        for (int i = 0; i < 4; ++i)
            lds4[d * 16 + ((((t & 3) << 2) + i) ^ swz)] = v[i];
    }
    // Xhi (tiled) straight from registers; 16-n window never crosses a 512-n tile
    {
        int dfull = dblk * 64 + d;
        int n0 = nblk * 64 + c0;
        unsigned short* dst = Xhi + (size_t)b * D_ * N_
                            + ((size_t)((dfull >> 4) * 32 + (n0 >> 9))) * 8192
                            + (dfull & 15) * 512 + (n0 & 511);
        s16x8 h0, h1;
#pragma unroll
        for (int k = 0; k < 8; ++k) {
            h0[k] = (short)f2bf(v[k >> 2][k & 3]);
            h1[k] = (short)f2bf(v[2 + (k >> 2)][k & 3]);
        }
        *reinterpret_cast<s16x8*>(dst) = h0;
        *reinterpret_cast<s16x8*>(dst + 8) = h1;
    }
    __syncthreads();
    // XT [N][D] from swizzled LDS: thread -> row n = t>>2, d's c0..c0+15
    {
        int n = t >> 2;
        const float* L = reinterpret_cast<const float*>(lds4);
        s16x8 h0, h1, l0, l1;
#pragma unroll
        for (int k = 0; k < 16; ++k) {
            int r = c0 + k;
            int sz = (r ^ (r >> 3)) & 7;
            float a = L[r * 64 + ((((n >> 2) ^ sz) << 2) | (n & 3))];
            unsigned short ha = f2bf(a);
            unsigned short la = f2bf(a - bf2f(ha));
            if (k < 8) { h0[k] = (short)ha; l0[k] = (short)la; }
            else       { h1[k - 8] = (short)ha; l1[k - 8] = (short)la; }
        }
        size_t off = ((size_t)b * N_ + nblk * 64 + n) * D_ + dblk * 64 + c0;
        *reinterpret_cast<s16x8*>(XThi + off) = h0;
        *reinterpret_cast<s16x8*>(XThi + off + 8) = h1;
        if (have_lo) {
            *reinterpret_cast<s16x8*>(XTlo + off) = l0;
            *reinterpret_cast<s16x8*>(XTlo + off + 8) = l1;
        }
    }
}

// ---------------- ginit ----------------
__global__ __launch_bounds__(256) void k_ginit(const float* __restrict__ Bin,
        float* __restrict__ bases, unsigned short* __restrict__ BThi,
        unsigned short* __restrict__ BTlo) {
    __shared__ float lds[64][65];
    int id = blockIdx.x, dblk = id & 7, b = id >> 3;
    int t = threadIdx.x, tn = t & 63, tq = t >> 6;
    const float* Bb = Bin + ((size_t)b * D_ + dblk * 64) * R_;
    float* bb = bases + ((size_t)b * D_ + dblk * 64) * R_;
#pragma unroll
    for (int i = 0; i < 16; ++i) {
        int d = i * 4 + tq;
        float v = Bb[d * R_ + tn];
        lds[d][tn] = v;
        bb[d * R_ + tn] = v;
    }
    __syncthreads();
#pragma unroll
    for (int i = 0; i < 16; ++i) {
        int r = i * 4 + tq;
        float v = lds[tn][r];
        unsigned short hi = f2bf(v);
        size_t off = ((size_t)b * R_ + r) * D_ + dblk * 64 + tn;
        BThi[off] = hi;
        BTlo[off] = f2bf(v - bf2f(hi));
    }
}

// ---------------- gram: G = B^T B (+ optional zero of Hf bank 0, pre-loop) ----------------
__global__ __launch_bounds__(256) void k_gram(const unsigned short* __restrict__ BT,
        unsigned short* __restrict__ G, float* __restrict__ Hf, int zf) {
    int b = blockIdx.x;
    int t = threadIdx.x, lane = t & 63, w = t >> 6;
    int m16 = lane & 15, h4 = lane >> 4;
    if (zf) {
        float* Hz = Hf + (size_t)b * 4096;
#pragma unroll
        for (int i = 0; i < 4; ++i)
            *reinterpret_cast<f32x4*>(Hz + i * 1024 + t * 4) = (f32x4){0.f, 0.f, 0.f, 0.f};
    }
    const unsigned short* BTb = BT + (size_t)b * R_ * D_;
    f32x4 acc[4];
#pragma unroll
    for (int j = 0; j < 4; ++j) acc[j] = (f32x4){0.f, 0.f, 0.f, 0.f};
#pragma unroll
    for (int k0 = 0; k0 < D_; k0 += 32) {
        int kg = k0 + (h4 << 3);
        s16x8 frag[4];
#pragma unroll
        for (int j = 0; j < 4; ++j)
            frag[j] = ld8(BTb + (size_t)(j * 16 + m16) * D_ + kg);
        s16x8 fw = ld8(BTb + (size_t)(w * 16 + m16) * D_ + kg);
#pragma unroll
        for (int j = 0; j < 4; ++j) acc[j] = MFMA16(fw, frag[j], acc[j]);
    }
    unsigned short* Gb = G + (size_t)b * R_ * R_;
#pragma unroll
    for (int j = 0; j < 4; ++j)
#pragma unroll
        for (int q = 0; q < 4; ++q) {
            int r1 = 16 * w + (h4 << 2) + q;
            Gb[r1 * R_ + 16 * j + m16] = f2bf(acc[j][q]);
        }
}

// ---------------- init: S (bf16x3) + softmax + den0 + coef1 ----------------
template <int LO>
__global__ __launch_bounds__(256, 2) void k_init(const unsigned short* __restrict__ XThi,
        const unsigned short* __restrict__ XTlo, const unsigned short* __restrict__ BThi,
        const unsigned short* __restrict__ BTlo, const unsigned short* __restrict__ G,
        unsigned short* __restrict__ CTb, unsigned short* __restrict__ Cnr) {
    __shared__ __align__(16) unsigned short xhbuf[2][16 * 512];
    __shared__ __align__(16) unsigned short xlbuf[LO ? 2 : 1][16 * 512];
    __shared__ __align__(16) unsigned short ldsc[16 * 64];
    __shared__ float red[2][4][16];
    int id = blockIdx.x, blk = id & 63, b = id >> 6;
    int t = threadIdx.x, lane = t & 63, w = t >> 6;
    int m16 = lane & 15, h4 = lane >> 4;
    const unsigned short* XTb = XThi + (size_t)b * N_ * D_;
    const unsigned short* XLb = XTlo + (size_t)b * N_ * D_;
    const unsigned short* BThb = BThi + (size_t)b * R_ * D_;
    const unsigned short* BTlb = BTlo + (size_t)b * R_ * D_;
    const unsigned short* Gb = G + (size_t)b * R_ * R_;
    unsigned short* CTbb = CTb + (size_t)b * R_ * N_;
    unsigned short* Cnrb = Cnr + (size_t)b * N_ * R_;
    s16x8 abh[16], abl[16], g[2];
#pragma unroll
    for (int ks = 0; ks < 16; ++ks) {
        size_t off = (size_t)(w * 16 + m16) * D_ + ks * 32 + h4 * 8;
        abh[ks] = ld8(BThb + off);
        abl[ks] = ld8(BTlb + off);
    }
#pragma unroll
    for (int ks = 0; ks < 2; ++ks)
        g[ks] = ld8(Gb + (size_t)(w * 16 + m16) * R_ + ks * 32 + h4 * 8);
    SCHEDB;
    stage16(XTb + (size_t)(blk * 16 + 0) * 16 * D_, D_, xhbuf[0], w, lane);
    if (LO) stage16(XLb + (size_t)(blk * 16 + 0) * 16 * D_, D_, xlbuf[0], w, lane);
    stage16(XTb + (size_t)(blk * 16 + 1) * 16 * D_, D_, xhbuf[1], w, lane);
    if (LO) stage16(XLb + (size_t)(blk * 16 + 1) * 16 * D_, D_, xlbuf[1], w, lane);
    SCHEDB;

    int swz = (m16 & 7) << 4;
    char* crow = reinterpret_cast<char*>(ldsc) + m16 * 128;

    for (int tt = 0; tt < 16; ++tt) {
        int cur = tt & 1;
        int n0 = (blk * 16 + tt) * 16;
        if (LO) {
            if (tt == 0) VMW(8);
            else if (tt == 15) VMW(5);
            else VMW(13);
        } else {
            if (tt == 0) VMW(4);
            else if (tt == 15) VMW(5);
            else VMW(9);
        }
        BARRIER;  // tile tt visible
        const unsigned short* xh = xhbuf[cur];
        const unsigned short* xl = xlbuf[LO ? cur : 0];
        f32x4 acc = (f32x4){0.f, 0.f, 0.f, 0.f};
#pragma unroll
        for (int ks = 0; ks < 16; ++ks) {
            s16x8 bh = read_t16(xh, m16, ks, h4);
            acc = MFMA16(abh[ks], bh, acc);
            acc = MFMA16(abl[ks], bh, acc);
            if (LO) {
                s16x8 bl = read_t16(xl, m16, ks, h4);
                acc = MFMA16(abh[ks], bl, acc);
            }
        }
        float mx = fmaxf(fmaxf(acc[0], acc[1]), fmaxf(acc[2], acc[3]));
        mx = fmaxf(mx, __shfl_xor(mx, 16));
        mx = fmaxf(mx, __shfl_xor(mx, 32));
        if (lane < 16) red[0][w][m16] = mx;
        LGKM0; BARRIER;
        mx = fmaxf(fmaxf(red[0][0][m16], red[0][1][m16]),
                   fmaxf(red[0][2][m16], red[0][3][m16]));
        float p[4], ss = 0.f;
#pragma unroll
        for (int q = 0; q < 4; ++q) {
            p[q] = __expf(INVT_ * (acc[q] - mx));
            ss += p[q];
        }
        ss += __shfl_xor(ss, 16);
        ss += __shfl_xor(ss, 32);
        if (lane < 16) red[1][w][m16] = ss;
        LGKM0; BARRIER;
        ss = red[1][0][m16] + red[1][1][m16] + red[1][2][m16] + red[1][3][m16];
        float inv = 1.f / ss;
#pragma unroll
        for (int q = 0; q < 4; ++q) {
            int r = w * 16 + h4 * 4 + q;
            *reinterpret_cast<unsigned short*>(crow + ((r * 2) ^ swz)) = f2bf(p[q] * inv);
        }
        LGKM0; BARRIER;
        f32x4 dacc = (f32x4){0.f, 0.f, 0.f, 0.f};
#pragma unroll
        for (int ks = 0; ks < 2; ++ks) {
            s16x8 bf = *reinterpret_cast<const s16x8*>(crow + ((ks * 64 + h4 * 16) ^ swz));
            dacc = MFMA16(g[ks], bf, dacc);
        }
        s16x4 cn;
        float c1v[4];
#pragma unroll
        for (int q = 0; q < 4; ++q) {
            c1v[q] = p[q] * inv * acc[q] / (dacc[q] + EPS_);
            cn[q] = (short)f2bf(c1v[q]);
        }
        LGKM0; BARRIER;
        SCHEDB;
#pragma unroll
        for (int q = 0; q < 4; ++q)
            CTbb[(size_t)(w * 16 + h4 * 4 + q) * N_ + n0 + m16] = f2bf(c1v[q]);
        *reinterpret_cast<s16x4*>(Cnrb + (size_t)(n0 + m16) * R_ + w * 16 + h4 * 4) = cn;
        SCHEDB;
        if (tt + 2 < 16) {
            stage16(XTb + (size_t)(blk * 16 + tt + 2) * 16 * D_, D_, xhbuf[cur], w, lane);
            if (LO) stage16(XLb + (size_t)(blk * 16 + tt + 2) * 16 * D_, D_, xlbuf[cur], w, lane);
        }
        SCHEDB;
    }
}

// ---------------- cu: coef update. grid 1024 = 8b x 128blk; 8 tiles of 16 n-rows ----------------
__global__ __launch_bounds__(256, 4) void k_cu(const unsigned short* __restrict__ XThi,
        const unsigned short* __restrict__ BThi, const unsigned short* __restrict__ G,
        unsigned short* __restrict__ CTb, unsigned short* __restrict__ Cnr) {
    __shared__ __align__(16) unsigned short xbuf[2][16 * 512];
    __shared__ __align__(16) unsigned short cbuf[2][16 * 64];
    int id = blockIdx.x, blk = id & 127, b = id >> 7;
    int t = threadIdx.x, lane = t & 63, w = t >> 6;
    int m16 = lane & 15, h4 = lane >> 4;
    const unsigned short* XTb = XThi + (size_t)b * N_ * D_;
    const unsigned short* BTb = BThi + (size_t)b * R_ * D_;
    const unsigned short* Gb = G + (size_t)b * R_ * R_;
    unsigned short* CTbb = CTb + (size_t)b * R_ * N_;
    unsigned short* Cnrb = Cnr + (size_t)b * N_ * R_;
    s16x8 abt[16], g[2];
#pragma unroll
    for (int ks = 0; ks < 16; ++ks)
        abt[ks] = ld8(BTb + (size_t)(w * 16 + m16) * D_ + ks * 32 + h4 * 8);
#pragma unroll
    for (int ks = 0; ks < 2; ++ks)
        g[ks] = ld8(Gb + (size_t)(w * 16 + m16) * R_ + ks * 32 + h4 * 8);
    SCHEDB;
    stage16(XTb + (size_t)(blk * 8 + 0) * 16 * D_, D_, xbuf[0], w, lane);
    stage_c16(Cnrb + (size_t)(blk * 8 + 0) * 16 * R_, cbuf[0], w, lane);
    stage16(XTb + (size_t)(blk * 8 + 1) * 16 * D_, D_, xbuf[1], w, lane);
    stage_c16(Cnrb + (size_t)(blk * 8 + 1) * 16 * R_, cbuf[1], w, lane);
    SCHEDB;

    for (int tt = 0; tt < 8; ++tt) {
        int cur = tt & 1;
        int n0 = (blk * 8 + tt) * 16;
        if (tt == 0) VMW(5);
        else if (tt == 7) VMW(5);
        else VMW(10);
        BARRIER;  // tile tt (X + Cnr) visible
        const unsigned short* xb = xbuf[cur];
        const unsigned short* cb = cbuf[cur];
        f32x4 acc = (f32x4){0.f, 0.f, 0.f, 0.f};
#pragma unroll
        for (int ks = 0; ks < 16; ++ks)
            acc = MFMA16(abt[ks], read_t16(xb, m16, ks, h4), acc);
        f32x4 dacc = (f32x4){0.f, 0.f, 0.f, 0.f};
#pragma unroll
        for (int ks = 0; ks < 2; ++ks)
            dacc = MFMA16(g[ks], read_c16(cb, m16, ks, h4), dacc);
        s16x4 cn;
        float c1v[4];
#pragma unroll
        for (int q = 0; q < 4; ++q) {
            int r = w * 16 + h4 * 4 + q;
            float cold = read_c_scalar(cb, m16, r);
            c1v[q] = cold * acc[q] / (dacc[q] + EPS_);
            cn[q] = (short)f2bf(c1v[q]);
        }
        LGKM0; BARRIER;
        SCHEDB;
#pragma unroll
        for (int q = 0; q < 4; ++q)
            CTbb[(size_t)(w * 16 + h4 * 4 + q) * N_ + n0 + m16] = f2bf(c1v[q]);
        *reinterpret_cast<s16x4*>(Cnrb + (size_t)(n0 + m16) * R_ + w * 16 + h4 * 4) = cn;
        SCHEDB;
        if (tt + 2 < 8) {
            stage16(XTb + (size_t)(blk * 8 + tt + 2) * 16 * D_, D_, xbuf[cur], w, lane);
            stage_c16(Cnrb + (size_t)(blk * 8 + tt + 2) * 16 * R_, cbuf[cur], w, lane);
        }
        SCHEDB;
    }
}

// ---------------- bu1t: num2^T partials (bf16) + fused H partials. grid 1024 = 8b x 32c x 4dg ----
// Xhi TILED; H partials accumulate via fp32 atomicAdd into Hf bank sp (k_hred deleted).
__global__ __launch_bounds__(256, 4) void k_bu1t(const unsigned short* __restrict__ Xhi,
        const unsigned short* __restrict__ CTb, unsigned short* __restrict__ wsN2,
        float* __restrict__ Hf, int sp) {
    __shared__ __align__(16) unsigned short xbuf[2][16 * 512];
    int id = blockIdx.x;
    int b = id >> 7, c = (id >> 2) & 31, dg = id & 3;
    int t = threadIdx.x, lane = t & 63, w = t >> 6;
    int m16 = lane & 15, h4 = lane >> 4;
    const unsigned short* Xb = Xhi + (size_t)b * D_ * N_;   // tiled base for batch
    const unsigned short* Cbc = CTb + (size_t)b * R_ * N_ + c * 512;
    s16x8 act[16];
#pragma unroll
    for (int ks = 0; ks < 16; ++ks)
        act[ks] = ld8(Cbc + (size_t)(w * 16 + m16) * N_ + ks * 32 + h4 * 8);
    SCHEDB;
    stage16(Xb + ((size_t)((dg * 8 + 0) * 32 + c)) * 8192, 512, xbuf[0], w, lane);
    stage16(Xb + ((size_t)((dg * 8 + 1) * 32 + c)) * 8192, 512, xbuf[1], w, lane);
    SCHEDB;
    // fused H partial (chunked; L2 loads + MFMAs overlap the staging HBM latency)
    f32x4 hacc = (f32x4){0.f, 0.f, 0.f, 0.f};
    {
        const unsigned short* Hrow = Cbc + (size_t)(dg * 16 + m16) * N_;
#pragma unroll
        for (int gg = 0; gg < 4; ++gg) {
            SCHEDB;
            s16x8 hb[4];
#pragma unroll
            for (int j = 0; j < 4; ++j)
                hb[j] = ld8(Hrow + (gg * 4 + j) * 32 + h4 * 8);
#pragma unroll
            for (int j = 0; j < 4; ++j)
                hacc = MFMA16(act[gg * 4 + j], hb[j], hacc);
        }
    }
    SCHEDB;
    unsigned short* n2 = wsN2 + (size_t)(b * 32 + c) * R_ * D_;
    for (int tt = 0; tt < 8; ++tt) {
        int cur = tt & 1;
        int d0 = dg * 128 + tt * 16;
        if (tt == 0) VMW(4);
        else if (tt == 7) VMW(4);
        else VMW(8);
        BARRIER;
        const unsigned short* xb = xbuf[cur];
        f32x4 acc = (f32x4){0.f, 0.f, 0.f, 0.f};
#pragma unroll
        for (int ks = 0; ks < 16; ++ks)
            acc = MFMA16(act[ks], read_t16(xb, m16, ks, h4), acc);
        LGKM0; BARRIER;  // xbuf[cur] reads done
        SCHEDB;
        if (tt + 2 < 8)
            stage16(Xb + ((size_t)((dg * 8 + tt + 2) * 32 + c)) * 8192, 512, xbuf[cur], w, lane);
        SCHEDB;
#pragma unroll
        for (int q = 0; q < 4; ++q)
            n2[(size_t)(w * 16 + h4 * 4 + q) * D_ + d0 + m16] = f2bf(acc[q]);
        SCHEDB;
    }
    float* Hfb = Hf + (size_t)sp * (B_ * 4096) + (size_t)b * 4096;
#pragma unroll
    for (int q = 0; q < 4; ++q)
        atomicAdd(&Hfb[(w * 16 + h4 * 4 + q) * R_ + dg * 16 + m16], hacc[q]);
}

// ---------------- bu2: den2 = bases*H, bases update. grid 256 = 8b x 32dblk ----------------
// Reads Hf bank sp; zeroes bank 1-sp. v2: N2 reduction via 16B vector loads into
// registers (identical c-order -> bit-identical), parked in LDS for the den loop.
__global__ __launch_bounds__(256) void k_bu2(const unsigned short* __restrict__ wsN2,
        float* __restrict__ Hf, int sp, float* __restrict__ bases,
        unsigned short* __restrict__ BThi, unsigned short* __restrict__ Bdr) {
    __shared__ float ldsH[64][64];   // [p][r]
    __shared__ float ldsb[16][65];   // bases [d][p]
    __shared__ float ldsn[16][65];   // new [d][r]
    __shared__ float ldsn2[64][17];  // reduced n2 [r][d], padded (+1 word -> <=2-way)
    int id = blockIdx.x, dblk = id & 31, b = id >> 5;
    int t = threadIdx.x;
    int d0 = dblk * 16;
    // zero other bank for next step's bu1t atomics (256 blocks x 128 floats = full bank)
    {
        float* Hz = Hf + (size_t)(1 - sp) * (B_ * 4096) + (size_t)id * 128;
        if (t < 32) *reinterpret_cast<f32x4*>(Hz + t * 4) = (f32x4){0.f, 0.f, 0.f, 0.f};
    }
    // N2 reduction: threads 0..127 -> (r = t>>1, d-half = t&1); 32 x s16x8 vector loads,
    // accumulated in c = 0..31 order (same per-element order as the old scalar gather).
    if (t < 128) {
        int r = t >> 1, hf = (t & 1) * 8;
        const unsigned short* base = wsN2 + (size_t)(b * 32) * R_ * D_ + (size_t)r * D_ + d0 + hf;
        float a[8];
#pragma unroll
        for (int k = 0; k < 8; ++k) a[k] = 0.f;
        for (int c = 0; c < 32; ++c) {
            s16x8 v = ld8(base + (size_t)c * R_ * D_);
#pragma unroll
            for (int k = 0; k < 8; ++k) a[k] += bf2f((unsigned short)v[k]);
        }
#pragma unroll
        for (int k = 0; k < 8; ++k) ldsn2[r][hf + k] = a[k];
    }
    const float* Hb = Hf + (size_t)sp * (B_ * 4096) + (size_t)b * 4096;
#pragma unroll
    for (int i = 0; i < 4; ++i) {
        f32x4 v = *reinterpret_cast<const f32x4*>(Hb + i * 1024 + t * 4);
        *reinterpret_cast<f32x4*>(&ldsH[0][0] + i * 1024 + t * 4) = v;
    }
    {
        int d = t >> 4, p0 = (t & 15) * 4;
        f32x4 v = *reinterpret_cast<const f32x4*>(bases + ((size_t)b * D_ + d0 + d) * R_ + p0);
#pragma unroll
        for (int k = 0; k < 4; ++k) ldsb[d][p0 + k] = v[k];
    }
    __syncthreads();
#pragma unroll
    for (int j = 0; j < 4; ++j) {
        int i = t + 256 * j;       // i = r*16 + d
        int r = i >> 4, d = i & 15;
        float n2 = ldsn2[r][d];
        float den = 0.f;
#pragma unroll 8
        for (int p = 0; p < 64; ++p) den += ldsb[d][p] * ldsH[p][r];
        ldsn[d][r] = ldsb[d][r] * n2 / (den + EPS_);
    }
    __syncthreads();
    {
        int d = t >> 4, r0 = (t & 15) * 4;
        f32x4 v;
        s16x4 hv;
#pragma unroll
        for (int k = 0; k < 4; ++k) {
            v[k] = ldsn[d][r0 + k];
            hv[k] = (short)f2bf(v[k]);
        }
        *reinterpret_cast<f32x4*>(bases + ((size_t)b * D_ + d0 + d) * R_ + r0) = v;
        *reinterpret_cast<s16x4*>((unsigned short*)Bdr + ((size_t)b * D_ + d0 + d) * R_ + r0) = hv;
    }
    {
        int r = t >> 2, dd = (t & 3) * 4;
        s16x4 hv;
#pragma unroll
        for (int k = 0; k < 4; ++k) hv[k] = (short)f2bf(ldsn[dd + k][r]);
        *reinterpret_cast<s16x4*>(BThi + ((size_t)b * R_ + r) * D_ + d0 + dd) = hv;
    }
}

// ---------------- out = bases * coef^T, LDS-transposed wide-store epilogue ----------------
__global__ __launch_bounds__(256, 2) void k_out(const unsigned short* __restrict__ Bdr,
        const unsigned short* __restrict__ Cnr, float* __restrict__ Out) {
    __shared__ float ldso[4][64 * 68 + 8];
    int id = blockIdx.x, nblk = id & 63, dblk = (id >> 6) & 7, b = id >> 9;
    int t = threadIdx.x, lane = t & 63, w = t >> 6;
    int m16 = lane & 15, h4 = lane >> 4;
    const unsigned short* Bb = Bdr + (size_t)b * D_ * R_;
    const unsigned short* Cb = Cnr + (size_t)b * N_ * R_;
    int d0 = dblk * 64, n0 = nblk * 256 + w * 64;
    f32x4 acc[4][4];
#pragma unroll
    for (int i = 0; i < 4; ++i)
#pragma unroll
        for (int j = 0; j < 4; ++j) acc[i][j] = (f32x4){0.f, 0.f, 0.f, 0.f};
#pragma unroll
    for (int k0 = 0; k0 < 64; k0 += 32) {
        int kg = k0 + (h4 << 3);
        s16x8 afrag[4], bfrag[4];
#pragma unroll
        for (int i = 0; i < 4; ++i)
            afrag[i] = ld8(Bb + (size_t)(d0 + i * 16 + m16) * R_ + kg);
#pragma unroll
        for (int j = 0; j < 4; ++j)
            bfrag[j] = ld8(Cb + (size_t)(n0 + j * 16 + m16) * R_ + kg);
#pragma unroll
        for (int i = 0; i < 4; ++i)
#pragma unroll
            for (int j = 0; j < 4; ++j)
                acc[i][j] = MFMA16(afrag[i], bfrag[j], acc[i][j]);
    }
#pragma unroll
    for (int i = 0; i < 4; ++i)
#pragma unroll
        for (int j = 0; j < 4; ++j)
#pragma unroll
            for (int q = 0; q < 4; ++q)
                ldso[w][(i * 16 + h4 * 4 + q) * 68 + j * 16 + m16] = acc[i][j][q];
    __syncthreads();
    float* Ob = Out + (size_t)b * D_ * N_ + (size_t)d0 * N_ + nblk * 256;
    int quad = lane >> 4, cc = (lane & 15) * 4;
#pragma unroll
    for (int i = 0; i < 16; ++i) {
        int d = w * 16 + i;
        f32x4 v = *reinterpret_cast<const f32x4*>(&ldso[quad][d * 68 + cc]);
        *reinterpret_cast<f32x4*>(Ob + (size_t)d * N_ + quad * 64 + cc) = v;
    }
}

}  // namespace

extern "C" void kernel_launch(void* const* d_in, const int* in_sizes, int n_in,
                              void* d_out, int out_size, void* d_ws, size_t ws_size,
                              hipStream_t stream) {
    const float* X = (const float*)d_in[0];
    const float* Bin = (const float*)d_in[1];
    float* Out = (float*)d_out;
    char* ws = (char*)d_ws;

    const size_t o_Xhi  = 0;
    const size_t o_XThi = o_Xhi  + (size_t)B_ * D_ * N_ * 2;
    const size_t o_CTb  = o_XThi + (size_t)B_ * N_ * D_ * 2;
    const size_t o_Cnr  = o_CTb  + (size_t)B_ * R_ * N_ * 2;
    const size_t o_bas  = o_Cnr  + (size_t)B_ * N_ * R_ * 2;
    const size_t o_BThi = o_bas  + (size_t)B_ * D_ * R_ * 4;
    const size_t o_BTlo = o_BThi + (size_t)B_ * R_ * D_ * 2;
    const size_t o_Bdr  = o_BTlo + (size_t)B_ * R_ * D_ * 2;
    const size_t o_G    = o_Bdr  + (size_t)B_ * D_ * R_ * 2;
    const size_t o_Hf   = o_G    + (size_t)B_ * R_ * R_ * 2;
    const size_t o_N2   = o_Hf   + (size_t)2 * B_ * R_ * R_ * 4;   // double-banked fp32 H
    const size_t BASE   = o_N2   + (size_t)B_ * 32 * R_ * D_ * 2;  // bf16 partials
    const size_t o_XTlo = BASE;
    const size_t FULL   = o_XTlo + (size_t)B_ * N_ * D_ * 2;

    if (ws_size < BASE) return;  // cannot run safely
    int have_lo = ws_size >= FULL ? 1 : 0;

    unsigned short* Xhi  = (unsigned short*)(ws + o_Xhi);
    unsigned short* XThi = (unsigned short*)(ws + o_XThi);
    unsigned short* XTlo = (unsigned short*)(ws + (have_lo ? o_XTlo : o_XThi));
    unsigned short* CTb  = (unsigned short*)(ws + o_CTb);
    unsigned short* Cnr  = (unsigned short*)(ws + o_Cnr);
    float*          bas  = (float*)(ws + o_bas);
    unsigned short* BThi = (unsigned short*)(ws + o_BThi);
    unsigned short* BTlo = (unsigned short*)(ws + o_BTlo);
    unsigned short* Bdr  = (unsigned short*)(ws + o_Bdr);
    unsigned short* G    = (unsigned short*)(ws + o_G);
    float*          Hf   = (float*)(ws + o_Hf);
    unsigned short* N2   = (unsigned short*)(ws + o_N2);

    k_convert<<<dim3(16384), dim3(256), 0, stream>>>(X, Xhi, XThi, XTlo, have_lo);
    k_ginit<<<dim3(64), dim3(256), 0, stream>>>(Bin, bas, BThi, BTlo);
    k_gram<<<dim3(8), dim3(256), 0, stream>>>(BThi, G, Hf, 1);   // also zeroes Hf bank 0
    if (have_lo)
        k_init<1><<<dim3(512), dim3(256), 0, stream>>>(XThi, XTlo, BThi, BTlo, G, CTb, Cnr);
    else
        k_init<0><<<dim3(512), dim3(256), 0, stream>>>(XThi, XTlo, BThi, BTlo, G, CTb, Cnr);
    for (int s = 0; s < 7; ++s) {
        int sp = s & 1;
        k_bu1t<<<dim3(1024), dim3(256), 0, stream>>>(Xhi, CTb, N2, Hf, sp);
        k_bu2<<<dim3(256), dim3(256), 0, stream>>>(N2, Hf, sp, bas, BThi, Bdr);
        k_gram<<<dim3(8), dim3(256), 0, stream>>>(BThi, G, Hf, 0);
        k_cu<<<dim3(1024), dim3(256), 0, stream>>>(XThi, BThi, G, CTb, Cnr);
    }
    k_out<<<dim3(4096), dim3(256), 0, stream>>>(Bdr, Cnr, Out);
}

// Round 12
// 1170.013 us; speedup vs baseline: 1.0211x; 1.0211x over previous
//
#include <hip/hip_runtime.h>
#include <cstdint>
#include <cstddef>

namespace {

constexpr int B_ = 8;
constexpr int D_ = 512;
constexpr int N_ = 16384;
constexpr int R_ = 64;
constexpr float EPS_ = 1e-6f;
constexpr float INVT_ = 100.0f;

typedef __attribute__((ext_vector_type(4))) float f32x4;
typedef __attribute__((ext_vector_type(8))) short s16x8;
typedef __attribute__((ext_vector_type(4))) short s16x4;

#define MFMA16(A, Bv, C) __builtin_amdgcn_mfma_f32_16x16x32_bf16(A, Bv, C, 0, 0, 0)

#define VMW(n) asm volatile("s_waitcnt vmcnt(" #n ")" ::: "memory")
#define LGKM0 asm volatile("s_waitcnt lgkmcnt(0)" ::: "memory")
#define SCHEDB __builtin_amdgcn_sched_barrier(0)
#define BARRIER do { SCHEDB; __builtin_amdgcn_s_barrier(); SCHEDB; } while (0)

typedef __attribute__((address_space(3))) unsigned int lds_u32_t;
typedef const __attribute__((address_space(1))) unsigned int glb_u32_t;

__device__ __forceinline__ void gl2lds16(const void* g, void* l) {
    __builtin_amdgcn_global_load_lds((glb_u32_t*)g, (lds_u32_t*)l, 16, 0, 0);
}

__device__ __forceinline__ unsigned short f2bf(float x) {
    unsigned int u = __float_as_uint(x);
    return (unsigned short)((u + 0x7fffu + ((u >> 16) & 1u)) >> 16);
}
__device__ __forceinline__ float bf2f(unsigned short u) {
    return __uint_as_float(((unsigned int)u) << 16);
}
__device__ __forceinline__ s16x8 ld8(const unsigned short* p) {
    return *reinterpret_cast<const s16x8*>(p);
}

// Stage a 16-row x 1KB tile into LDS: wave w stages rows w*4..w*4+4 (4 ops).
// Source col pre-XOR'd with ((row&7)<<4) so swizzled reads are conflict-free.
__device__ __forceinline__ void stage16(const unsigned short* __restrict__ rowbase,
        size_t rstride_elems, unsigned short* __restrict__ buf, int w, int lane) {
#pragma unroll
    for (int i = 0; i < 4; ++i) {
        int r = w * 4 + i;
        const char* src = reinterpret_cast<const char*>(rowbase + (size_t)r * rstride_elems)
                        + ((lane << 4) ^ ((r & 7) << 4));
        gl2lds16(src, reinterpret_cast<char*>(buf) + r * 1024);
    }
}
// read B-frag: row (0..15), k-step ks, h4 = lane>>4
__device__ __forceinline__ s16x8 read_t16(const unsigned short* buf, int row, int ks, int h4) {
    return *reinterpret_cast<const s16x8*>(reinterpret_cast<const char*>(buf)
        + row * 1024 + ((ks * 64 + h4 * 16) ^ ((row & 7) << 4)));
}
// Stage a 16-row x 128B Cnr tile (2 KB): wave's (w&1) half; waves 2,3 duplicate 0,1.
__device__ __forceinline__ void stage_c16(const unsigned short* __restrict__ cnr_n0,
        unsigned short* __restrict__ buf, int w, int lane) {
    int h = w & 1;
    int row = h * 8 + (lane >> 3);
    const char* src = reinterpret_cast<const char*>(cnr_n0 + (size_t)row * R_)
                    + ((((lane & 7) ^ (row & 7))) << 4);
    gl2lds16(src, reinterpret_cast<char*>(buf) + h * 1024);
}
__device__ __forceinline__ s16x8 read_c16(const unsigned short* buf, int row, int ks, int h4) {
    return *reinterpret_cast<const s16x8*>(reinterpret_cast<const char*>(buf)
        + row * 128 + ((ks * 64 + h4 * 16) ^ ((row & 7) << 4)));
}
__device__ __forceinline__ float read_c_scalar(const unsigned short* buf, int row, int r) {
    return bf2f(*reinterpret_cast<const unsigned short*>(
        reinterpret_cast<const char*>(buf) + row * 128 + ((r * 2) ^ ((row & 7) << 4))));
}

// ---------------- convert: X fp32 -> X_hi TILED [dt][nt][16][512], XT_hi/XT_lo [N][D] ----
// 64x64 tile (16KB LDS, 24 VGPR, ~74% occupancy — R6-proven form).
// Xhi tiled layout: element (d,n) at ((d>>4)*32 + (n>>9))*8192 + (d&15)*512 + (n&511).
__global__ __launch_bounds__(256) void k_convert(const float* __restrict__ X,
        unsigned short* __restrict__ Xhi, unsigned short* __restrict__ XThi,
        unsigned short* __restrict__ XTlo, int have_lo) {
    __shared__ f32x4 lds4[64 * 16];   // 16 KB, row stride 16 vectors (64 floats), swizzled
    int id = blockIdx.x;
    int nblk = id & 255, dblk = (id >> 8) & 7, b = id >> 11;
    int t = threadIdx.x;
    int d = t >> 2, c0 = (t & 3) * 16;
    const float* Xb = X + ((size_t)b * D_ + dblk * 64) * N_ + (size_t)nblk * 64;
    f32x4 v[4];
#pragma unroll
    for (int i = 0; i < 4; ++i)
        v[i] = *reinterpret_cast<const f32x4*>(Xb + (size_t)d * N_ + c0 + 4 * i);
    {
        int swz = (d ^ (d >> 3)) & 7;
#pragma unroll
        for (int i = 0; i < 4; ++i)
            lds4[d * 16 + ((((t & 3) << 2) + i) ^ swz)] = v[i];
    }
    // Xhi (tiled) straight from registers; 16-n window never crosses a 512-n tile
    {
        int dfull = dblk * 64 + d;
        int n0 = nblk * 64 + c0;
        unsigned short* dst = Xhi + (size_t)b * D_ * N_
                            + ((size_t)((dfull >> 4) * 32 + (n0 >> 9))) * 8192
                            + (dfull & 15) * 512 + (n0 & 511);
        s16x8 h0, h1;
#pragma unroll
        for (int k = 0; k < 8; ++k) {
            h0[k] = (short)f2bf(v[k >> 2][k & 3]);
            h1[k] = (short)f2bf(v[2 + (k >> 2)][k & 3]);
        }
        *reinterpret_cast<s16x8*>(dst) = h0;
        *reinterpret_cast<s16x8*>(dst + 8) = h1;
    }
    __syncthreads();
    // XT [N][D] from swizzled LDS: thread -> row n = t>>2, d's c0..c0+15
    {
        int n = t >> 2;
        const float* L = reinterpret_cast<const float*>(lds4);
        s16x8 h0, h1, l0, l1;
#pragma unroll
        for (int k = 0; k < 16; ++k) {
            int r = c0 + k;
            int sz = (r ^ (r >> 3)) & 7;
            float a = L[r * 64 + ((((n >> 2) ^ sz) << 2) | (n & 3))];
            unsigned short ha = f2bf(a);
            unsigned short la = f2bf(a - bf2f(ha));
            if (k < 8) { h0[k] = (short)ha; l0[k] = (short)la; }
            else       { h1[k - 8] = (short)ha; l1[k - 8] = (short)la; }
        }
        size_t off = ((size_t)b * N_ + nblk * 64 + n) * D_ + dblk * 64 + c0;
        *reinterpret_cast<s16x8*>(XThi + off) = h0;
        *reinterpret_cast<s16x8*>(XThi + off + 8) = h1;
        if (have_lo) {
            *reinterpret_cast<s16x8*>(XTlo + off) = l0;
            *reinterpret_cast<s16x8*>(XTlo + off + 8) = l1;
        }
    }
}

// ---------------- ginit ----------------
__global__ __launch_bounds__(256) void k_ginit(const float* __restrict__ Bin,
        float* __restrict__ bases, unsigned short* __restrict__ BThi,
        unsigned short* __restrict__ BTlo) {
    __shared__ float lds[64][65];
    int id = blockIdx.x, dblk = id & 7, b = id >> 3;
    int t = threadIdx.x, tn = t & 63, tq = t >> 6;
    const float* Bb = Bin + ((size_t)b * D_ + dblk * 64) * R_;
    float* bb = bases + ((size_t)b * D_ + dblk * 64) * R_;
#pragma unroll
    for (int i = 0; i < 16; ++i) {
        int d = i * 4 + tq;
        float v = Bb[d * R_ + tn];
        lds[d][tn] = v;
        bb[d * R_ + tn] = v;
    }
    __syncthreads();
#pragma unroll
    for (int i = 0; i < 16; ++i) {
        int r = i * 4 + tq;
        float v = lds[tn][r];
        unsigned short hi = f2bf(v);
        size_t off = ((size_t)b * R_ + r) * D_ + dblk * 64 + tn;
        BThi[off] = hi;
        BTlo[off] = f2bf(v - bf2f(hi));
    }
}

// ---------------- gram: G = B^T B (+ optional zero of Hf bank 0, pre-loop) ----------------
__global__ __launch_bounds__(256) void k_gram(const unsigned short* __restrict__ BT,
        unsigned short* __restrict__ G, float* __restrict__ Hf, int zf) {
    int b = blockIdx.x;
    int t = threadIdx.x, lane = t & 63, w = t >> 6;
    int m16 = lane & 15, h4 = lane >> 4;
    if (zf) {
        float* Hz = Hf + (size_t)b * 4096;
#pragma unroll
        for (int i = 0; i < 4; ++i)
            *reinterpret_cast<f32x4*>(Hz + i * 1024 + t * 4) = (f32x4){0.f, 0.f, 0.f, 0.f};
    }
    const unsigned short* BTb = BT + (size_t)b * R_ * D_;
    f32x4 acc[4];
#pragma unroll
    for (int j = 0; j < 4; ++j) acc[j] = (f32x4){0.f, 0.f, 0.f, 0.f};
#pragma unroll
    for (int k0 = 0; k0 < D_; k0 += 32) {
        int kg = k0 + (h4 << 3);
        s16x8 frag[4];
#pragma unroll
        for (int j = 0; j < 4; ++j)
            frag[j] = ld8(BTb + (size_t)(j * 16 + m16) * D_ + kg);
        s16x8 fw = ld8(BTb + (size_t)(w * 16 + m16) * D_ + kg);
#pragma unroll
        for (int j = 0; j < 4; ++j) acc[j] = MFMA16(fw, frag[j], acc[j]);
    }
    unsigned short* Gb = G + (size_t)b * R_ * R_;
#pragma unroll
    for (int j = 0; j < 4; ++j)
#pragma unroll
        for (int q = 0; q < 4; ++q) {
            int r1 = 16 * w + (h4 << 2) + q;
            Gb[r1 * R_ + 16 * j + m16] = f2bf(acc[j][q]);
        }
}

// ---------------- init: S (bf16x3) + softmax + den0 + coef1 ----------------
template <int LO>
__global__ __launch_bounds__(256, 2) void k_init(const unsigned short* __restrict__ XThi,
        const unsigned short* __restrict__ XTlo, const unsigned short* __restrict__ BThi,
        const unsigned short* __restrict__ BTlo, const unsigned short* __restrict__ G,
        unsigned short* __restrict__ CTb, unsigned short* __restrict__ Cnr) {
    __shared__ __align__(16) unsigned short xhbuf[2][16 * 512];
    __shared__ __align__(16) unsigned short xlbuf[LO ? 2 : 1][16 * 512];
    __shared__ __align__(16) unsigned short ldsc[16 * 64];
    __shared__ float red[2][4][16];
    int id = blockIdx.x, blk = id & 63, b = id >> 6;
    int t = threadIdx.x, lane = t & 63, w = t >> 6;
    int m16 = lane & 15, h4 = lane >> 4;
    const unsigned short* XTb = XThi + (size_t)b * N_ * D_;
    const unsigned short* XLb = XTlo + (size_t)b * N_ * D_;
    const unsigned short* BThb = BThi + (size_t)b * R_ * D_;
    const unsigned short* BTlb = BTlo + (size_t)b * R_ * D_;
    const unsigned short* Gb = G + (size_t)b * R_ * R_;
    unsigned short* CTbb = CTb + (size_t)b * R_ * N_;
    unsigned short* Cnrb = Cnr + (size_t)b * N_ * R_;
    s16x8 abh[16], abl[16], g[2];
#pragma unroll
    for (int ks = 0; ks < 16; ++ks) {
        size_t off = (size_t)(w * 16 + m16) * D_ + ks * 32 + h4 * 8;
        abh[ks] = ld8(BThb + off);
        abl[ks] = ld8(BTlb + off);
    }
#pragma unroll
    for (int ks = 0; ks < 2; ++ks)
        g[ks] = ld8(Gb + (size_t)(w * 16 + m16) * R_ + ks * 32 + h4 * 8);
    SCHEDB;
    stage16(XTb + (size_t)(blk * 16 + 0) * 16 * D_, D_, xhbuf[0], w, lane);
    if (LO) stage16(XLb + (size_t)(blk * 16 + 0) * 16 * D_, D_, xlbuf[0], w, lane);
    stage16(XTb + (size_t)(blk * 16 + 1) * 16 * D_, D_, xhbuf[1], w, lane);
    if (LO) stage16(XLb + (size_t)(blk * 16 + 1) * 16 * D_, D_, xlbuf[1], w, lane);
    SCHEDB;

    int swz = (m16 & 7) << 4;
    char* crow = reinterpret_cast<char*>(ldsc) + m16 * 128;

    for (int tt = 0; tt < 16; ++tt) {
        int cur = tt & 1;
        int n0 = (blk * 16 + tt) * 16;
        if (LO) {
            if (tt == 0) VMW(8);
            else if (tt == 15) VMW(5);
            else VMW(13);
        } else {
            if (tt == 0) VMW(4);
            else if (tt == 15) VMW(5);
            else VMW(9);
        }
        BARRIER;  // tile tt visible
        const unsigned short* xh = xhbuf[cur];
        const unsigned short* xl = xlbuf[LO ? cur : 0];
        f32x4 acc = (f32x4){0.f, 0.f, 0.f, 0.f};
#pragma unroll
        for (int ks = 0; ks < 16; ++ks) {
            s16x8 bh = read_t16(xh, m16, ks, h4);
            acc = MFMA16(abh[ks], bh, acc);
            acc = MFMA16(abl[ks], bh, acc);
            if (LO) {
                s16x8 bl = read_t16(xl, m16, ks, h4);
                acc = MFMA16(abh[ks], bl, acc);
            }
        }
        float mx = fmaxf(fmaxf(acc[0], acc[1]), fmaxf(acc[2], acc[3]));
        mx = fmaxf(mx, __shfl_xor(mx, 16));
        mx = fmaxf(mx, __shfl_xor(mx, 32));
        if (lane < 16) red[0][w][m16] = mx;
        LGKM0; BARRIER;
        mx = fmaxf(fmaxf(red[0][0][m16], red[0][1][m16]),
                   fmaxf(red[0][2][m16], red[0][3][m16]));
        float p[4], ss = 0.f;
#pragma unroll
        for (int q = 0; q < 4; ++q) {
            p[q] = __expf(INVT_ * (acc[q] - mx));
            ss += p[q];
        }
        ss += __shfl_xor(ss, 16);
        ss += __shfl_xor(ss, 32);
        if (lane < 16) red[1][w][m16] = ss;
        LGKM0; BARRIER;
        ss = red[1][0][m16] + red[1][1][m16] + red[1][2][m16] + red[1][3][m16];
        float inv = 1.f / ss;
#pragma unroll
        for (int q = 0; q < 4; ++q) {
            int r = w * 16 + h4 * 4 + q;
            *reinterpret_cast<unsigned short*>(crow + ((r * 2) ^ swz)) = f2bf(p[q] * inv);
        }
        LGKM0; BARRIER;
        f32x4 dacc = (f32x4){0.f, 0.f, 0.f, 0.f};
#pragma unroll
        for (int ks = 0; ks < 2; ++ks) {
            s16x8 bf = *reinterpret_cast<const s16x8*>(crow + ((ks * 64 + h4 * 16) ^ swz));
            dacc = MFMA16(g[ks], bf, dacc);
        }
        s16x4 cn;
        float c1v[4];
#pragma unroll
        for (int q = 0; q < 4; ++q) {
            c1v[q] = p[q] * inv * acc[q] / (dacc[q] + EPS_);
            cn[q] = (short)f2bf(c1v[q]);
        }
        LGKM0; BARRIER;
        SCHEDB;
#pragma unroll
        for (int q = 0; q < 4; ++q)
            CTbb[(size_t)(w * 16 + h4 * 4 + q) * N_ + n0 + m16] = f2bf(c1v[q]);
        *reinterpret_cast<s16x4*>(Cnrb + (size_t)(n0 + m16) * R_ + w * 16 + h4 * 4) = cn;
        SCHEDB;
        if (tt + 2 < 16) {
            stage16(XTb + (size_t)(blk * 16 + tt + 2) * 16 * D_, D_, xhbuf[cur], w, lane);
            if (LO) stage16(XLb + (size_t)(blk * 16 + tt + 2) * 16 * D_, D_, xlbuf[cur], w, lane);
        }
        SCHEDB;
    }
}

// ---------------- cu: coef update. grid 1024 = 8b x 128blk; 8 tiles of 16 n-rows ----------------
__global__ __launch_bounds__(256, 4) void k_cu(const unsigned short* __restrict__ XThi,
        const unsigned short* __restrict__ BThi, const unsigned short* __restrict__ G,
        unsigned short* __restrict__ CTb, unsigned short* __restrict__ Cnr) {
    __shared__ __align__(16) unsigned short xbuf[2][16 * 512];
    __shared__ __align__(16) unsigned short cbuf[2][16 * 64];
    int id = blockIdx.x, blk = id & 127, b = id >> 7;
    int t = threadIdx.x, lane = t & 63, w = t >> 6;
    int m16 = lane & 15, h4 = lane >> 4;
    const unsigned short* XTb = XThi + (size_t)b * N_ * D_;
    const unsigned short* BTb = BThi + (size_t)b * R_ * D_;
    const unsigned short* Gb = G + (size_t)b * R_ * R_;
    unsigned short* CTbb = CTb + (size_t)b * R_ * N_;
    unsigned short* Cnrb = Cnr + (size_t)b * N_ * R_;
    s16x8 abt[16], g[2];
#pragma unroll
    for (int ks = 0; ks < 16; ++ks)
        abt[ks] = ld8(BTb + (size_t)(w * 16 + m16) * D_ + ks * 32 + h4 * 8);
#pragma unroll
    for (int ks = 0; ks < 2; ++ks)
        g[ks] = ld8(Gb + (size_t)(w * 16 + m16) * R_ + ks * 32 + h4 * 8);
    SCHEDB;
    stage16(XTb + (size_t)(blk * 8 + 0) * 16 * D_, D_, xbuf[0], w, lane);
    stage_c16(Cnrb + (size_t)(blk * 8 + 0) * 16 * R_, cbuf[0], w, lane);
    stage16(XTb + (size_t)(blk * 8 + 1) * 16 * D_, D_, xbuf[1], w, lane);
    stage_c16(Cnrb + (size_t)(blk * 8 + 1) * 16 * R_, cbuf[1], w, lane);
    SCHEDB;

    for (int tt = 0; tt < 8; ++tt) {
        int cur = tt & 1;
        int n0 = (blk * 8 + tt) * 16;
        if (tt == 0) VMW(5);
        else if (tt == 7) VMW(5);
        else VMW(10);
        BARRIER;  // tile tt (X + Cnr) visible
        const unsigned short* xb = xbuf[cur];
        const unsigned short* cb = cbuf[cur];
        f32x4 acc = (f32x4){0.f, 0.f, 0.f, 0.f};
#pragma unroll
        for (int ks = 0; ks < 16; ++ks)
            acc = MFMA16(abt[ks], read_t16(xb, m16, ks, h4), acc);
        f32x4 dacc = (f32x4){0.f, 0.f, 0.f, 0.f};
#pragma unroll
        for (int ks = 0; ks < 2; ++ks)
            dacc = MFMA16(g[ks], read_c16(cb, m16, ks, h4), dacc);
        s16x4 cn;
        float c1v[4];
#pragma unroll
        for (int q = 0; q < 4; ++q) {
            int r = w * 16 + h4 * 4 + q;
            float cold = read_c_scalar(cb, m16, r);
            c1v[q] = cold * acc[q] / (dacc[q] + EPS_);
            cn[q] = (short)f2bf(c1v[q]);
        }
        LGKM0; BARRIER;
        SCHEDB;
#pragma unroll
        for (int q = 0; q < 4; ++q)
            CTbb[(size_t)(w * 16 + h4 * 4 + q) * N_ + n0 + m16] = f2bf(c1v[q]);
        *reinterpret_cast<s16x4*>(Cnrb + (size_t)(n0 + m16) * R_ + w * 16 + h4 * 4) = cn;
        SCHEDB;
        if (tt + 2 < 8) {
            stage16(XTb + (size_t)(blk * 8 + tt + 2) * 16 * D_, D_, xbuf[cur], w, lane);
            stage_c16(Cnrb + (size_t)(blk * 8 + tt + 2) * 16 * R_, cbuf[cur], w, lane);
        }
        SCHEDB;
    }
}

// ---------------- bu1t: num2^T partials (bf16) + fused H partials. grid 1024 = 8b x 32c x 4dg ----
// Xhi TILED; H partials accumulate via fp32 atomicAdd into Hf bank sp (k_hred deleted).
__global__ __launch_bounds__(256, 4) void k_bu1t(const unsigned short* __restrict__ Xhi,
        const unsigned short* __restrict__ CTb, unsigned short* __restrict__ wsN2,
        float* __restrict__ Hf, int sp) {
    __shared__ __align__(16) unsigned short xbuf[2][16 * 512];
    int id = blockIdx.x;
    int b = id >> 7, c = (id >> 2) & 31, dg = id & 3;
    int t = threadIdx.x, lane = t & 63, w = t >> 6;
    int m16 = lane & 15, h4 = lane >> 4;
    const unsigned short* Xb = Xhi + (size_t)b * D_ * N_;   // tiled base for batch
    const unsigned short* Cbc = CTb + (size_t)b * R_ * N_ + c * 512;
    s16x8 act[16];
#pragma unroll
    for (int ks = 0; ks < 16; ++ks)
        act[ks] = ld8(Cbc + (size_t)(w * 16 + m16) * N_ + ks * 32 + h4 * 8);
    SCHEDB;
    stage16(Xb + ((size_t)((dg * 8 + 0) * 32 + c)) * 8192, 512, xbuf[0], w, lane);
    stage16(Xb + ((size_t)((dg * 8 + 1) * 32 + c)) * 8192, 512, xbuf[1], w, lane);
    SCHEDB;
    // fused H partial (chunked; L2 loads + MFMAs overlap the staging HBM latency)
    f32x4 hacc = (f32x4){0.f, 0.f, 0.f, 0.f};
    {
        const unsigned short* Hrow = Cbc + (size_t)(dg * 16 + m16) * N_;
#pragma unroll
        for (int gg = 0; gg < 4; ++gg) {
            SCHEDB;
            s16x8 hb[4];
#pragma unroll
            for (int j = 0; j < 4; ++j)
                hb[j] = ld8(Hrow + (gg * 4 + j) * 32 + h4 * 8);
#pragma unroll
            for (int j = 0; j < 4; ++j)
                hacc = MFMA16(act[gg * 4 + j], hb[j], hacc);
        }
    }
    SCHEDB;
    unsigned short* n2 = wsN2 + (size_t)(b * 32 + c) * R_ * D_;
    for (int tt = 0; tt < 8; ++tt) {
        int cur = tt & 1;
        int d0 = dg * 128 + tt * 16;
        if (tt == 0) VMW(4);
        else if (tt == 7) VMW(4);
        else VMW(8);
        BARRIER;
        const unsigned short* xb = xbuf[cur];
        f32x4 acc = (f32x4){0.f, 0.f, 0.f, 0.f};
#pragma unroll
        for (int ks = 0; ks < 16; ++ks)
            acc = MFMA16(act[ks], read_t16(xb, m16, ks, h4), acc);
        LGKM0; BARRIER;  // xbuf[cur] reads done
        SCHEDB;
        if (tt + 2 < 8)
            stage16(Xb + ((size_t)((dg * 8 + tt + 2) * 32 + c)) * 8192, 512, xbuf[cur], w, lane);
        SCHEDB;
#pragma unroll
        for (int q = 0; q < 4; ++q)
            n2[(size_t)(w * 16 + h4 * 4 + q) * D_ + d0 + m16] = f2bf(acc[q]);
        SCHEDB;
    }
    float* Hfb = Hf + (size_t)sp * (B_ * 4096) + (size_t)b * 4096;
#pragma unroll
    for (int q = 0; q < 4; ++q)
        atomicAdd(&Hfb[(w * 16 + h4 * 4 + q) * R_ + dg * 16 + m16], hacc[q]);
}

// ---------------- bu2: den2 = bases*H, bases update. grid 256 = 8b x 32dblk ----------------
// Reads Hf bank sp (atomically accumulated by bu1t); zeroes bank 1-sp for next step.
__global__ __launch_bounds__(256) void k_bu2(const unsigned short* __restrict__ wsN2,
        float* __restrict__ Hf, int sp, float* __restrict__ bases,
        unsigned short* __restrict__ BThi, unsigned short* __restrict__ Bdr) {
    __shared__ float ldsH[64][64];   // [p][r]
    __shared__ float ldsb[16][65];   // bases [d][p]
    __shared__ float ldsn[16][65];   // new [d][r]
    int id = blockIdx.x, dblk = id & 31, b = id >> 5;
    int t = threadIdx.x;
    int d0 = dblk * 16;
    // zero other bank for next step's bu1t atomics (256 blocks x 128 floats = full bank)
    {
        float* Hz = Hf + (size_t)(1 - sp) * (B_ * 4096) + (size_t)id * 128;
        if (t < 32) *reinterpret_cast<f32x4*>(Hz + t * 4) = (f32x4){0.f, 0.f, 0.f, 0.f};
    }
    const float* Hb = Hf + (size_t)sp * (B_ * 4096) + (size_t)b * 4096;
#pragma unroll
    for (int i = 0; i < 4; ++i) {
        f32x4 v = *reinterpret_cast<const f32x4*>(Hb + i * 1024 + t * 4);
        *reinterpret_cast<f32x4*>(&ldsH[0][0] + i * 1024 + t * 4) = v;
    }
    {
        int d = t >> 4, p0 = (t & 15) * 4;
        f32x4 v = *reinterpret_cast<const f32x4*>(bases + ((size_t)b * D_ + d0 + d) * R_ + p0);
#pragma unroll
        for (int k = 0; k < 4; ++k) ldsb[d][p0 + k] = v[k];
    }
    __syncthreads();
#pragma unroll
    for (int j = 0; j < 4; ++j) {
        int i = t + 256 * j;       // i = r*16 + d
        int r = i >> 4, d = i & 15;
        float n2 = 0.f;
        for (int c = 0; c < 32; ++c)
            n2 += bf2f(wsN2[(((size_t)b * 32 + c) * R_ + r) * D_ + d0 + d]);
        float den = 0.f;
#pragma unroll 8
        for (int p = 0; p < 64; ++p) den += ldsb[d][p] * ldsH[p][r];
        ldsn[d][r] = ldsb[d][r] * n2 / (den + EPS_);
    }
    __syncthreads();
    {
        int d = t >> 4, r0 = (t & 15) * 4;
        f32x4 v;
        s16x4 hv;
#pragma unroll
        for (int k = 0; k < 4; ++k) {
            v[k] = ldsn[d][r0 + k];
            hv[k] = (short)f2bf(v[k]);
        }
        *reinterpret_cast<f32x4*>(bases + ((size_t)b * D_ + d0 + d) * R_ + r0) = v;
        *reinterpret_cast<s16x4*>((unsigned short*)Bdr + ((size_t)b * D_ + d0 + d) * R_ + r0) = hv;
    }
    {
        int r = t >> 2, dd = (t & 3) * 4;
        s16x4 hv;
#pragma unroll
        for (int k = 0; k < 4; ++k) hv[k] = (short)f2bf(ldsn[dd + k][r]);
        *reinterpret_cast<s16x4*>(BThi + ((size_t)b * R_ + r) * D_ + d0 + dd) = hv;
    }
}

// ---------------- out = bases * coef^T, LDS-transposed wide-store epilogue ----------------
__global__ __launch_bounds__(256, 2) void k_out(const unsigned short* __restrict__ Bdr,
        const unsigned short* __restrict__ Cnr, float* __restrict__ Out) {
    __shared__ float ldso[4][64 * 68 + 8];
    int id = blockIdx.x, nblk = id & 63, dblk = (id >> 6) & 7, b = id >> 9;
    int t = threadIdx.x, lane = t & 63, w = t >> 6;
    int m16 = lane & 15, h4 = lane >> 4;
    const unsigned short* Bb = Bdr + (size_t)b * D_ * R_;
    const unsigned short* Cb = Cnr + (size_t)b * N_ * R_;
    int d0 = dblk * 64, n0 = nblk * 256 + w * 64;
    f32x4 acc[4][4];
#pragma unroll
    for (int i = 0; i < 4; ++i)
#pragma unroll
        for (int j = 0; j < 4; ++j) acc[i][j] = (f32x4){0.f, 0.f, 0.f, 0.f};
#pragma unroll
    for (int k0 = 0; k0 < 64; k0 += 32) {
        int kg = k0 + (h4 << 3);
        s16x8 afrag[4], bfrag[4];
#pragma unroll
        for (int i = 0; i < 4; ++i)
            afrag[i] = ld8(Bb + (size_t)(d0 + i * 16 + m16) * R_ + kg);
#pragma unroll
        for (int j = 0; j < 4; ++j)
            bfrag[j] = ld8(Cb + (size_t)(n0 + j * 16 + m16) * R_ + kg);
#pragma unroll
        for (int i = 0; i < 4; ++i)
#pragma unroll
            for (int j = 0; j < 4; ++j)
                acc[i][j] = MFMA16(afrag[i], bfrag[j], acc[i][j]);
    }
#pragma unroll
    for (int i = 0; i < 4; ++i)
#pragma unroll
        for (int j = 0; j < 4; ++j)
#pragma unroll
            for (int q = 0; q < 4; ++q)
                ldso[w][(i * 16 + h4 * 4 + q) * 68 + j * 16 + m16] = acc[i][j][q];
    __syncthreads();
    float* Ob = Out + (size_t)b * D_ * N_ + (size_t)d0 * N_ + nblk * 256;
    int quad = lane >> 4, cc = (lane & 15) * 4;
#pragma unroll
    for (int i = 0; i < 16; ++i) {
        int d = w * 16 + i;
        f32x4 v = *reinterpret_cast<const f32x4*>(&ldso[quad][d * 68 + cc]);
        *reinterpret_cast<f32x4*>(Ob + (size_t)d * N_ + quad * 64 + cc) = v;
    }
}

}  // namespace

extern "C" void kernel_launch(void* const* d_in, const int* in_sizes, int n_in,
                              void* d_out, int out_size, void* d_ws, size_t ws_size,
                              hipStream_t stream) {
    const float* X = (const float*)d_in[0];
    const float* Bin = (const float*)d_in[1];
    float* Out = (float*)d_out;
    char* ws = (char*)d_ws;

    const size_t o_Xhi  = 0;
    const size_t o_XThi = o_Xhi  + (size_t)B_ * D_ * N_ * 2;
    const size_t o_CTb  = o_XThi + (size_t)B_ * N_ * D_ * 2;
    const size_t o_Cnr  = o_CTb  + (size_t)B_ * R_ * N_ * 2;
    const size_t o_bas  = o_Cnr  + (size_t)B_ * N_ * R_ * 2;
    const size_t o_BThi = o_bas  + (size_t)B_ * D_ * R_ * 4;
    const size_t o_BTlo = o_BThi + (size_t)B_ * R_ * D_ * 2;
    const size_t o_Bdr  = o_BTlo + (size_t)B_ * R_ * D_ * 2;
    const size_t o_G    = o_Bdr  + (size_t)B_ * D_ * R_ * 2;
    const size_t o_Hf   = o_G    + (size_t)B_ * R_ * R_ * 2;
    const size_t o_N2   = o_Hf   + (size_t)2 * B_ * R_ * R_ * 4;   // double-banked fp32 H
    const size_t BASE   = o_N2   + (size_t)B_ * 32 * R_ * D_ * 2;  // bf16 partials
    const size_t o_XTlo = BASE;
    const size_t FULL   = o_XTlo + (size_t)B_ * N_ * D_ * 2;

    if (ws_size < BASE) return;  // cannot run safely
    int have_lo = ws_size >= FULL ? 1 : 0;

    unsigned short* Xhi  = (unsigned short*)(ws + o_Xhi);
    unsigned short* XThi = (unsigned short*)(ws + o_XThi);
    unsigned short* XTlo = (unsigned short*)(ws + (have_lo ? o_XTlo : o_XThi));
    unsigned short* CTb  = (unsigned short*)(ws + o_CTb);
    unsigned short* Cnr  = (unsigned short*)(ws + o_Cnr);
    float*          bas  = (float*)(ws + o_bas);
    unsigned short* BThi = (unsigned short*)(ws + o_BThi);
    unsigned short* BTlo = (unsigned short*)(ws + o_BTlo);
    unsigned short* Bdr  = (unsigned short*)(ws + o_Bdr);
    unsigned short* G    = (unsigned short*)(ws + o_G);
    float*          Hf   = (float*)(ws + o_Hf);
    unsigned short* N2   = (unsigned short*)(ws + o_N2);

    k_convert<<<dim3(16384), dim3(256), 0, stream>>>(X, Xhi, XThi, XTlo, have_lo);
    k_ginit<<<dim3(64), dim3(256), 0, stream>>>(Bin, bas, BThi, BTlo);
    k_gram<<<dim3(8), dim3(256), 0, stream>>>(BThi, G, Hf, 1);   // also zeroes Hf bank 0
    if (have_lo)
        k_init<1><<<dim3(512), dim3(256), 0, stream>>>(XThi, XTlo, BThi, BTlo, G, CTb, Cnr);
    else
        k_init<0><<<dim3(512), dim3(256), 0, stream>>>(XThi, XTlo, BThi, BTlo, G, CTb, Cnr);
    for (int s = 0; s < 7; ++s) {
        int sp = s & 1;
        k_bu1t<<<dim3(1024), dim3(256), 0, stream>>>(Xhi, CTb, N2, Hf, sp);
        k_bu2<<<dim3(256), dim3(256), 0, stream>>>(N2, Hf, sp, bas, BThi, Bdr);
        k_gram<<<dim3(8), dim3(256), 0, stream>>>(BThi, G, Hf, 0);
        k_cu<<<dim3(1024), dim3(256), 0, stream>>>(XThi, BThi, G, CTb, Cnr);
    }
    k_out<<<dim3(4096), dim3(256), 0, stream>>>(Bdr, Cnr, Out);
}